// Round 9
// baseline (295.620 us; speedup 1.0000x reference)
//
#include <hip/hip_runtime.h>
#include <math.h>

#define N_NODES 50000
#define N_EDGES 800000
#define ET (N_EDGES + N_NODES)   // with self-loops
#define FDIM 128
#define HEADS 4
#define HID 32
#define NCLS 8
#define NEG 0.2f
#define EPS_BN 1e-5f

#define BSH 8                                   // 256 nodes per bucket
#define NBUCK ((N_NODES + 255) >> BSH)          // 196
#define EPB 4096                                // edges per partition block
#define PB ((ET + EPB - 1) / EPB)               // 208

typedef __attribute__((ext_vector_type(8))) short short8;
typedef __attribute__((ext_vector_type(4))) float f32x4;

__device__ __forceinline__ float lrelu(float e) { return e > 0.f ? e : NEG * e; }
__device__ __forceinline__ float bflo(unsigned u) { return __uint_as_float(u << 16); }
__device__ __forceinline__ float bfhi(unsigned u) { return __uint_as_float(u & 0xffff0000u); }
__device__ __forceinline__ unsigned f2bf(float f) {           // RNE round to bf16 bits
    unsigned b = __float_as_uint(f);
    return (b + 0x7fffu + ((b >> 16) & 1u)) >> 16;
}

// ---------------- fused prep: bucket histogram + x->bf16 cast + W0/W1 packing ----------------

#define CAST_B 3125   // 50000*128/8/256
#define PACK_B 64     // 16384/256

__global__ __launch_bounds__(256) void prep_and_hist(
        const int* __restrict__ ei, int* __restrict__ bhist,
        const float* __restrict__ x, unsigned short* __restrict__ xb,
        const float* __restrict__ W0, unsigned short* __restrict__ W0p,
        const float* __restrict__ W1, unsigned short* __restrict__ W1p) {
    __shared__ unsigned h[NBUCK];
    int b = blockIdx.x, tid = threadIdx.x;
    if (b < PB) {
        int e0 = b * EPB;
        for (int i = tid; i < NBUCK; i += 256) h[i] = 0;
        __syncthreads();
        #pragma unroll
        for (int k = 0; k < EPB / 256; k++) {
            int e = e0 + k * 256 + tid;
            if (e < ET) {
                int d = (e < N_EDGES) ? ei[N_EDGES + e] : (e - N_EDGES);
                atomicAdd(&h[d >> BSH], 1u);
            }
        }
        __syncthreads();
        for (int i = tid; i < NBUCK; i += 256)
            if (h[i]) atomicAdd(&bhist[i], (int)h[i]);
    } else if (b < PB + CAST_B) {
        int i = (b - PB) * 256 + tid;
        const float4* p = (const float4*)x + (size_t)i * 2;
        float4 a = p[0], c = p[1];
        uint4 o;
        o.x = f2bf(a.x) | (f2bf(a.y) << 16);
        o.y = f2bf(a.z) | (f2bf(a.w) << 16);
        o.z = f2bf(c.x) | (f2bf(c.y) << 16);
        o.w = f2bf(c.z) | (f2bf(c.w) << 16);
        ((uint4*)xb)[i] = o;
    } else {
        int pb = b - PB - CAST_B;
        const float* W = (pb < PACK_B) ? W0 : W1;
        unsigned short* Wp = (pb < PACK_B) ? W0p : W1p;
        int o = (pb & (PACK_B - 1)) * 256 + tid;
        int j = o & 7, lane = (o >> 3) & 63, kc = (o >> 9) & 3, t = o >> 11;
        int k = kc * 32 + ((lane >> 4) << 3) + j;
        int n = t * 16 + (lane & 15);
        Wp[o] = (unsigned short)f2bf(W[k * 128 + n]);
    }
}

// single-block exclusive scan of 196 bucket counts -> boffs, bcur; offs[N] = ET
__global__ __launch_bounds__(256) void scan_buckets(const int* __restrict__ bhist,
                                                    int* __restrict__ boffs,
                                                    int* __restrict__ bcur,
                                                    int* __restrict__ offs) {
    __shared__ int s[256];
    int tid = threadIdx.x;
    int v = (tid < NBUCK) ? bhist[tid] : 0;
    s[tid] = v;
    __syncthreads();
    for (int off = 1; off < 256; off <<= 1) {
        int x = (tid >= off) ? s[tid - off] : 0;
        __syncthreads();
        s[tid] += x;
        __syncthreads();
    }
    int excl = s[tid] - v;
    if (tid < NBUCK) { boffs[tid] = excl; bcur[tid] = excl; }
    if (tid == 0) { boffs[NBUCK] = ET; offs[N_NODES] = ET; }
}

// pass A: LDS-histogram radix partition into bucket regions
__global__ __launch_bounds__(256) void partition_pairs(const int* __restrict__ ei,
                                                       int* __restrict__ bcur,
                                                       int2* __restrict__ pairs) {
    __shared__ unsigned hist[NBUCK];
    __shared__ unsigned base[NBUCK];
    int tid = threadIdx.x;
    int e0 = blockIdx.x * EPB;
    for (int i = tid; i < NBUCK; i += 256) hist[i] = 0;
    __syncthreads();
    #pragma unroll
    for (int k = 0; k < EPB / 256; k++) {
        int e = e0 + k * 256 + tid;
        if (e < ET) {
            int d = (e < N_EDGES) ? ei[N_EDGES + e] : (e - N_EDGES);
            atomicAdd(&hist[d >> BSH], 1u);
        }
    }
    __syncthreads();
    for (int i = tid; i < NBUCK; i += 256) {
        unsigned h = hist[i];
        base[i] = h ? (unsigned)atomicAdd(&bcur[i], (int)h) : 0u;
        hist[i] = 0;
    }
    __syncthreads();
    #pragma unroll
    for (int k = 0; k < EPB / 256; k++) {
        int e = e0 + k * 256 + tid;
        if (e < ET) {
            int s, d;
            if (e < N_EDGES) { s = ei[e]; d = ei[N_EDGES + e]; }
            else             { s = d = e - N_EDGES; }
            int b = d >> BSH;
            unsigned lpos = atomicAdd(&hist[b], 1u);
            pairs[base[b] + lpos] = make_int2(s, d);
        }
    }
}

// pass B: per bucket, derive per-node offsets in LDS, write offs coalesced, regroup
__global__ __launch_bounds__(256) void group_bucket(const int2* __restrict__ pairs,
                                                    const int* __restrict__ boffs,
                                                    int* __restrict__ offs,
                                                    int* __restrict__ ssrc) {
    __shared__ int cnt[256];
    __shared__ int pfx[256];
    int b = blockIdx.x, tid = threadIdx.x;
    int n0 = b << BSH;
    int base = boffs[b], end = boffs[b + 1];
    cnt[tid] = 0;
    __syncthreads();
    for (int i = base + tid; i < end; i += 256)
        atomicAdd(&cnt[pairs[i].y & 255], 1);
    __syncthreads();
    int v = cnt[tid];
    pfx[tid] = v;
    __syncthreads();
    for (int off = 1; off < 256; off <<= 1) {
        int x = (tid >= off) ? pfx[tid - off] : 0;
        __syncthreads();
        pfx[tid] += x;
        __syncthreads();
    }
    int excl = pfx[tid] - v;
    if (n0 + tid < N_NODES) offs[n0 + tid] = base + excl;
    cnt[tid] = excl;                 // reuse as cursor
    __syncthreads();
    for (int i = base + tid; i < end; i += 256) {
        int2 p = pairs[i];
        int pos = atomicAdd(&cnt[p.y & 255], 1);
        ssrc[base + pos] = p.x;
    }
}

// ------- fused MFMA GEMM (M x 128 @ 128 x 128) + bf16 h-store + attn coeffs -------

__global__ __launch_bounds__(256) void gemm_attn(
        const unsigned short* __restrict__ Ab, const unsigned short* __restrict__ Wp,
        const float* __restrict__ att_s, const float* __restrict__ att_d,
        unsigned short* __restrict__ Hb, float* __restrict__ asn, float* __restrict__ adn,
        int M) {
    __shared__ float tiles[64 * 132];
    int tid = threadIdx.x;
    int wv = tid >> 6, lane = tid & 63;
    int base = blockIdx.x * 64;
    int mrow = base + wv * 16 + (lane & 15);
    if (mrow >= M) mrow = M - 1;
    int koff = (lane >> 4) * 8;

    f32x4 acc[8];
    #pragma unroll
    for (int t = 0; t < 8; t++) acc[t] = (f32x4){0.f, 0.f, 0.f, 0.f};

    #pragma unroll
    for (int kc = 0; kc < 4; kc++) {
        short8 a = *(const short8*)(Ab + (size_t)mrow * 128 + kc * 32 + koff);
        #pragma unroll
        for (int t = 0; t < 8; t++) {
            short8 b = *(const short8*)(Wp + (((t * 4 + kc) * 64 + lane) << 3));
            acc[t] = __builtin_amdgcn_mfma_f32_16x16x32_bf16(a, b, acc[t], 0, 0, 0);
        }
    }

    int rbase = wv * 16 + (lane >> 4) * 4;
    int col = lane & 15;
    #pragma unroll
    for (int t = 0; t < 8; t++)
        #pragma unroll
        for (int r = 0; r < 4; r++)
            tiles[(rbase + r) * 132 + t * 16 + col] = acc[t][r];
    __syncthreads();

    #pragma unroll
    for (int it = 0; it < 4; it++) {
        int u = tid + it * 256;
        int rl = u >> 4, cg = u & 15;
        int row = base + rl;
        if (row < M) {
            const float* p = tiles + rl * 132 + cg * 8;
            float4 v0 = *(const float4*)(p);
            float4 v1 = *(const float4*)(p + 4);
            uint4 o;
            o.x = f2bf(v0.x) | (f2bf(v0.y) << 16);
            o.y = f2bf(v0.z) | (f2bf(v0.w) << 16);
            o.z = f2bf(v1.x) | (f2bf(v1.y) << 16);
            o.w = f2bf(v1.z) | (f2bf(v1.w) << 16);
            *(uint4*)(Hb + (size_t)row * 128 + cg * 8) = o;
        }
    }

    {
        int rl = tid >> 2, hd = tid & 3;
        int row = base + rl;
        if (row < M) {
            const float* hrow = tiles + rl * 132 + hd * 32;
            const float* as = att_s + hd * 32;
            const float* ad = att_d + hd * 32;
            float ps = 0.f, pd = 0.f;
            #pragma unroll
            for (int i = 0; i < 8; i++) {
                float4 hv = *(const float4*)(hrow + i * 4);
                float4 sv = *(const float4*)(as + i * 4);
                float4 dv = *(const float4*)(ad + i * 4);
                ps += hv.x * sv.x + hv.y * sv.y + hv.z * sv.z + hv.w * sv.w;
                pd += hv.x * dv.x + hv.y * dv.y + hv.z * dv.z + hv.w * dv.w;
            }
            asn[row * 4 + hd] = ps;
            adn[row * 4 + hd] = pd;
        }
    }
}

// ------- aggregation + bias + BN + ELU (layers 0,1): one wave/node -------
// Phase C: lane owns 4 channels (uint2 = 8 B); half-wave 0 takes even edges, half-wave 1
// odd -> one load instruction covers 2 edges. src stored as pre-multiplied byte offset.
// Final shfl_xor(32) folds the halves; epilogue on 32 lanes x 4 channels.

__global__ __launch_bounds__(256) void aggregate(
        const unsigned short* __restrict__ hb, const float* __restrict__ asn,
        const float* __restrict__ adn, const int* __restrict__ offs,
        const int* __restrict__ ssrc, const float* __restrict__ bias,
        const float* __restrict__ gamma, const float* __restrict__ beta,
        const float* __restrict__ rmean, const float* __restrict__ rvar,
        unsigned short* __restrict__ outb) {
    __shared__ int2 sPair[4][4][72];   // [wave][head][slot]; stride 72
    int wv = threadIdx.x >> 6;
    int node = blockIdx.x * 4 + wv;
    if (node >= N_NODES) return;
    int lane = threadIdx.x & 63;
    int half = lane >> 5;              // even/odd edge stream
    int cl = lane & 31;                // channel quad: 4cl..4cl+3
    int hd = lane >> 4;                // head for sweep (16 lanes per head, unchanged)
    int beg = offs[node], deg = offs[node + 1] - beg;
    float4 ad4 = *(const float4*)(adn + node * 4);

    float4 den4 = make_float4(0.f, 0.f, 0.f, 0.f);
    float a0 = 0.f, a1 = 0.f, a2 = 0.f, a3 = 0.f;
    const char* hbase = (const char*)hb + cl * 8;   // this lane's 8-byte channel slice
    int hsel = (cl >> 3);                           // head of the OWNED channels
    const int2* pp = &sPair[wv][hsel][0];

    auto phaseC = [&](int cnt) {
        int bound = (cnt + 15) & ~15;
        for (int i = 0; i < bound; i += 16) {
            int2 p0 = pp[i + 0 + half],  p1 = pp[i + 2 + half];
            int2 p2 = pp[i + 4 + half],  p3 = pp[i + 6 + half];
            int2 p4 = pp[i + 8 + half],  p5 = pp[i + 10 + half];
            int2 p6 = pp[i + 12 + half], p7 = pp[i + 14 + half];
            uint2 u0 = *(const uint2*)(hbase + (unsigned)p0.x);
            uint2 u1 = *(const uint2*)(hbase + (unsigned)p1.x);
            uint2 u2 = *(const uint2*)(hbase + (unsigned)p2.x);
            uint2 u3 = *(const uint2*)(hbase + (unsigned)p3.x);
            uint2 u4 = *(const uint2*)(hbase + (unsigned)p4.x);
            uint2 u5 = *(const uint2*)(hbase + (unsigned)p5.x);
            uint2 u6 = *(const uint2*)(hbase + (unsigned)p6.x);
            uint2 u7 = *(const uint2*)(hbase + (unsigned)p7.x);
            float w0 = __int_as_float(p0.y), w1 = __int_as_float(p1.y);
            float w2 = __int_as_float(p2.y), w3 = __int_as_float(p3.y);
            float w4 = __int_as_float(p4.y), w5 = __int_as_float(p5.y);
            float w6 = __int_as_float(p6.y), w7 = __int_as_float(p7.y);
            a0 += w0 * bflo(u0.x); a1 += w0 * bfhi(u0.x); a2 += w0 * bflo(u0.y); a3 += w0 * bfhi(u0.y);
            a0 += w1 * bflo(u1.x); a1 += w1 * bfhi(u1.x); a2 += w1 * bflo(u1.y); a3 += w1 * bfhi(u1.y);
            a0 += w2 * bflo(u2.x); a1 += w2 * bfhi(u2.x); a2 += w2 * bflo(u2.y); a3 += w2 * bfhi(u2.y);
            a0 += w3 * bflo(u3.x); a1 += w3 * bfhi(u3.x); a2 += w3 * bflo(u3.y); a3 += w3 * bfhi(u3.y);
            a0 += w4 * bflo(u4.x); a1 += w4 * bfhi(u4.x); a2 += w4 * bflo(u4.y); a3 += w4 * bfhi(u4.y);
            a0 += w5 * bflo(u5.x); a1 += w5 * bfhi(u5.x); a2 += w5 * bflo(u5.y); a3 += w5 * bfhi(u5.y);
            a0 += w6 * bflo(u6.x); a1 += w6 * bfhi(u6.x); a2 += w6 * bflo(u6.y); a3 += w6 * bfhi(u6.y);
            a0 += w7 * bflo(u7.x); a1 += w7 * bfhi(u7.x); a2 += w7 * bflo(u7.y); a3 += w7 * bfhi(u7.y);
        }
    };

    for (int base0 = 0; base0 < deg; base0 += 64) {
        int j = base0 + lane;
        int soff = 0;
        float4 w4v = make_float4(0.f, 0.f, 0.f, 0.f);
        if (j < deg) {
            int s = ssrc[beg + j];
            soff = s << 8;                           // byte offset into 256 B rows
            float4 a = *(const float4*)(asn + s * 4);
            w4v.x = __expf(lrelu(a.x + ad4.x));
            w4v.y = __expf(lrelu(a.y + ad4.y));
            w4v.z = __expf(lrelu(a.z + ad4.z));
            w4v.w = __expf(lrelu(a.w + ad4.w));
            den4.x += w4v.x; den4.y += w4v.y; den4.z += w4v.z; den4.w += w4v.w;
        }
        sPair[wv][0][lane] = make_int2(soff, __float_as_int(w4v.x));
        sPair[wv][1][lane] = make_int2(soff, __float_as_int(w4v.y));
        sPair[wv][2][lane] = make_int2(soff, __float_as_int(w4v.z));
        sPair[wv][3][lane] = make_int2(soff, __float_as_int(w4v.w));
        int cnt = deg - base0; if (cnt > 64) cnt = 64;
        phaseC(cnt);
    }
    (void)hd;

    // fold even/odd halves, then reduce den across wave
    a0 += __shfl_xor(a0, 32); a1 += __shfl_xor(a1, 32);
    a2 += __shfl_xor(a2, 32); a3 += __shfl_xor(a3, 32);
    #pragma unroll
    for (int off = 32; off; off >>= 1) {
        den4.x += __shfl_xor(den4.x, off);
        den4.y += __shfl_xor(den4.y, off);
        den4.z += __shfl_xor(den4.z, off);
        den4.w += __shfl_xor(den4.w, off);
    }
    if (half == 0) {
        float den = (hsel & 2) ? ((hsel & 1) ? den4.w : den4.z)
                               : ((hsel & 1) ? den4.y : den4.x);
        float inv = 1.f / (den + 1e-16f);
        int c0 = cl * 4;
        float4 bi = *(const float4*)(bias + c0);
        float4 gm = *(const float4*)(gamma + c0);
        float4 bt = *(const float4*)(beta + c0);
        float4 rm = *(const float4*)(rmean + c0);
        float4 rv = *(const float4*)(rvar + c0);
        float o0 = a0 * inv + bi.x, o1 = a1 * inv + bi.y;
        float o2 = a2 * inv + bi.z, o3 = a3 * inv + bi.w;
        o0 = (o0 - rm.x) * rsqrtf(rv.x + EPS_BN) * gm.x + bt.x;
        o1 = (o1 - rm.y) * rsqrtf(rv.y + EPS_BN) * gm.y + bt.y;
        o2 = (o2 - rm.z) * rsqrtf(rv.z + EPS_BN) * gm.z + bt.z;
        o3 = (o3 - rm.w) * rsqrtf(rv.w + EPS_BN) * gm.w + bt.w;
        o0 = (o0 > 0.f) ? o0 : expm1f(o0);
        o1 = (o1 > 0.f) ? o1 : expm1f(o1);
        o2 = (o2 > 0.f) ? o2 : expm1f(o2);
        o3 = (o3 > 0.f) ? o3 : expm1f(o3);
        uint2 ob;
        ob.x = f2bf(o0) | (f2bf(o1) << 16);
        ob.y = f2bf(o2) | (f2bf(o3) << 16);
        *(uint2*)(outb + (size_t)node * 128 + c0) = ob;
    }
}

// ---------------- layer 2: fused GEMM(128->8) + attn coeffs (bf16 input) ----------------

__global__ __launch_bounds__(256) void gemm2_fused(
        const unsigned short* __restrict__ xb, const float* __restrict__ W2,
        const float* __restrict__ as2, const float* __restrict__ ad2,
        float* __restrict__ h2, float* __restrict__ asn, float* __restrict__ adn) {
    __shared__ float sW[128 * 8];
    __shared__ float sas[8], sad[8];
    int tid = threadIdx.x;
    for (int i = tid; i < 1024; i += 256) sW[i] = W2[i];
    if (tid < 8) { sas[tid] = as2[tid]; sad[tid] = ad2[tid]; }
    __syncthreads();
    int node = blockIdx.x * 256 + tid;
    if (node >= N_NODES) return;
    const uint4* xr = (const uint4*)(xb + (size_t)node * 128);
    float acc[8];
    #pragma unroll
    for (int c = 0; c < 8; c++) acc[c] = 0.f;
    for (int k8 = 0; k8 < 16; k8++) {
        uint4 u = xr[k8];
        float f[8] = { bflo(u.x), bfhi(u.x), bflo(u.y), bfhi(u.y),
                       bflo(u.z), bfhi(u.z), bflo(u.w), bfhi(u.w) };
        int kb = k8 * 8;
        #pragma unroll
        for (int q = 0; q < 8; q++)
            #pragma unroll
            for (int c = 0; c < 8; c++)
                acc[c] += f[q] * sW[(kb + q) * 8 + c];
    }
    float ps = 0.f, pd = 0.f;
    #pragma unroll
    for (int c = 0; c < 8; c++) {
        h2[(size_t)node * 8 + c] = acc[c];
        ps += acc[c] * sas[c];
        pd += acc[c] * sad[c];
    }
    asn[node] = ps;
    adn[node] = pd;
}

// ------- layer 2 aggregation + bias + log_softmax: one wave/node (no max pass) -------

__global__ __launch_bounds__(256) void aggregate2(
        const float* __restrict__ h2, const float* __restrict__ asn,
        const float* __restrict__ adn, const int* __restrict__ offs,
        const int* __restrict__ ssrc, const float* __restrict__ b2,
        float* __restrict__ out) {
    __shared__ int2 sPair[4][64];
    int wv = threadIdx.x >> 6;
    int node = blockIdx.x * 4 + wv;
    if (node >= N_NODES) return;
    int lane = threadIdx.x & 63;
    int g = lane >> 3, c = lane & 7;
    int beg = offs[node], end = offs[node + 1];
    int deg = end - beg;
    float adv = adn[node];

    float den = 0.f, acc = 0.f;
    auto phaseC = [&](int cnt) {
        int nIt = (cnt + 15) >> 4;
        const int2* pp = &sPair[wv][0];
        for (int i = 0; i < nIt; i++) {
            int e = i * 16 + g;
            int2 p0 = pp[e];
            int2 p1 = pp[e + 8];
            acc += __int_as_float(p0.y) * h2[(((unsigned)p0.x) << 3) + c];
            acc += __int_as_float(p1.y) * h2[(((unsigned)p1.x) << 3) + c];
        }
    };

    for (int base = 0; base < deg; base += 64) {
        int j = base + lane;
        int s = 0; float w = 0.f;
        if (j < deg) {
            s = ssrc[beg + j];
            w = __expf(lrelu(asn[s] + adv));
            den += w;
        }
        sPair[wv][lane] = make_int2(s, __float_as_int(w));
        int cnt = deg - base; if (cnt > 64) cnt = 64;
        phaseC(cnt);
    }

    acc += __shfl_xor(acc, 8); acc += __shfl_xor(acc, 16); acc += __shfl_xor(acc, 32);
    #pragma unroll
    for (int off = 32; off; off >>= 1) den += __shfl_xor(den, off);

    float o = acc / (den + 1e-16f) + b2[c];
    float mx = o;
    mx = fmaxf(mx, __shfl_xor(mx, 1));
    mx = fmaxf(mx, __shfl_xor(mx, 2));
    mx = fmaxf(mx, __shfl_xor(mx, 4));
    float ex = __expf(o - mx);
    float sm = ex;
    sm += __shfl_xor(sm, 1); sm += __shfl_xor(sm, 2); sm += __shfl_xor(sm, 4);
    if (g == 0) out[(size_t)node * 8 + c] = o - mx - logf(sm);
}

// ---------------- launch ----------------

extern "C" void kernel_launch(void* const* d_in, const int* in_sizes, int n_in,
                              void* d_out, int out_size, void* d_ws, size_t ws_size,
                              hipStream_t stream) {
    const float* x   = (const float*)d_in[0];
    const int*   ei  = (const int*)d_in[1];
    const float* W0  = (const float*)d_in[2];
    const float* as0 = (const float*)d_in[3];
    const float* ad0 = (const float*)d_in[4];
    const float* b0  = (const float*)d_in[5];
    const float* g0  = (const float*)d_in[6];
    const float* bb0 = (const float*)d_in[7];
    const float* rm0 = (const float*)d_in[8];
    const float* rv0 = (const float*)d_in[9];
    const float* W1  = (const float*)d_in[10];
    const float* as1 = (const float*)d_in[11];
    const float* ad1 = (const float*)d_in[12];
    const float* b1  = (const float*)d_in[13];
    const float* g1  = (const float*)d_in[14];
    const float* bb1 = (const float*)d_in[15];
    const float* rm1 = (const float*)d_in[16];
    const float* rv1 = (const float*)d_in[17];
    const float* W2  = (const float*)d_in[18];
    const float* as2 = (const float*)d_in[19];
    const float* ad2 = (const float*)d_in[20];
    const float* b2  = (const float*)d_in[21];
    float* out = (float*)d_out;

    char* w = (char*)d_ws;
    size_t off = 0;
    auto carve = [&](size_t bytes) {
        void* p = w + off;
        off += (bytes + 255) & ~(size_t)255;
        return p;
    };
    unsigned short* xb   = (unsigned short*)carve((size_t)N_NODES * 128 * 2);
    unsigned short* Hb   = (unsigned short*)carve((size_t)N_NODES * 128 * 2);
    unsigned short* Xb   = (unsigned short*)carve((size_t)N_NODES * 128 * 2);
    unsigned short* W0p  = (unsigned short*)carve(16384 * 2);
    unsigned short* W1p  = (unsigned short*)carve(16384 * 2);
    int*   offs   = (int*)carve((size_t)(N_NODES + 1) * 4);
    int*   bhist  = (int*)carve((size_t)NBUCK * 4);
    int*   boffs  = (int*)carve((size_t)(NBUCK + 1) * 4);
    int*   bcur   = (int*)carve((size_t)NBUCK * 4);
    int*   ssrc   = (int*)carve((size_t)ET * 4);
    int2*  pairs  = (int2*)carve((size_t)ET * 8);
    float* asn    = (float*)carve((size_t)N_NODES * 4 * 4);
    float* adn    = (float*)carve((size_t)N_NODES * 4 * 4);
    float* h2     = (float*)carve((size_t)N_NODES * 8 * 4);
    float* as2n   = (float*)carve((size_t)N_NODES * 4);
    float* ad2n   = (float*)carve((size_t)N_NODES * 4);
    (void)ws_size; (void)in_sizes; (void)n_in; (void)out_size;

    const int NB = (N_NODES + 255) / 256;
    const int GB = (N_NODES + 63) / 64;

    hipMemsetAsync(bhist, 0, (size_t)NBUCK * 4, stream);
    prep_and_hist<<<PB + CAST_B + 2 * PACK_B, 256, 0, stream>>>(ei, bhist, x, xb,
                                                                W0, W0p, W1, W1p);
    scan_buckets<<<1, 256, 0, stream>>>(bhist, boffs, bcur, offs);
    partition_pairs<<<PB, 256, 0, stream>>>(ei, bcur, pairs);
    group_bucket<<<NBUCK, 256, 0, stream>>>(pairs, boffs, offs, ssrc);

    gemm_attn<<<GB, 256, 0, stream>>>(xb, W0p, as0, ad0, Hb, asn, adn, N_NODES);
    aggregate<<<(N_NODES + 3) / 4, 256, 0, stream>>>(Hb, asn, adn, offs, ssrc,
                                                     b0, g0, bb0, rm0, rv0, Xb);
    gemm_attn<<<GB, 256, 0, stream>>>(Xb, W1p, as1, ad1, Hb, asn, adn, N_NODES);
    aggregate<<<(N_NODES + 3) / 4, 256, 0, stream>>>(Hb, asn, adn, offs, ssrc,
                                                     b1, g1, bb1, rm1, rv1, Xb);
    gemm2_fused<<<NB, 256, 0, stream>>>(Xb, W2, as2, ad2, h2, as2n, ad2n);
    aggregate2<<<(N_NODES + 3) / 4, 256, 0, stream>>>(h2, as2n, ad2n, offs, ssrc, b2, out);
}